// Round 1
// 239.481 us; speedup vs baseline: 1.0349x; 1.0349x over previous
//
#include <hip/hip_runtime.h>

// Shapes: input  (8, 256, 256, 64) fp32, NHWC
//         pooled (8,  64,  64, 64) fp32 (in d_ws, 8 MiB)
//         output (8, 256, 256, 64) fp32
// POOL=6, STRIDE=4, SAME padding -> pad_lo = 1 in both spatial dims.
//
// R2: (a) pool: 4x1 vertical strip per thread (18 rows x 6 cols = 108 loads
//     for 4 outputs; register sliding row-sum kills the cross-XCD vertical
//     re-read). (b) upsample: 4x4 output tile per thread from a 3x3 pooled
//     neighborhood (9 taps for 16 outputs; cuts 537MB logical gather to 75MB).

#define B_  8
#define H_  256
#define W_  256
#define C_  64
#define HP  64
#define WP  64
#define CG  16            // float4 channel groups per pixel
#define RS4 (W_ * C_ / 4) // input row stride in float4 units = 4096
#define CS4 (C_ / 4)      // input col stride in float4 units = 16

__device__ __forceinline__ float4 f4add(float4 a, float4 b) {
    return make_float4(a.x + b.x, a.y + b.y, a.z + b.z, a.w + b.w);
}
__device__ __forceinline__ float4 f4z() { return make_float4(0.f, 0.f, 0.f, 0.f); }

// ---------------- Kernel 1: 6x6 stride-4 SAME avg pool ----------------
// Thread = (b, t, j, cg): computes pooled[i0..i0+3][j] for i0 = 4t.
// Input rows needed: r0 = 16t-1 .. 16t+16 (18 rows). Output k's window is
// rr in [4k, 4k+5] of that strip (<=2 outputs share each row).
__global__ __launch_bounds__(256) void pool_kernel(const float* __restrict__ in,
                                                   float* __restrict__ pooled) {
    int gid = blockIdx.x * blockDim.x + threadIdx.x;
    int cg = gid & (CG - 1);
    int j  = (gid >> 4) & (WP - 1);
    int t  = (gid >> 10) & 15;
    int b  = gid >> 14;

    int cs = j * 4 - 1;          // leftmost window col (may be -1)
    int r0 = t * 16 - 1;         // first strip row (may be -1)
    bool c0v = (j > 0);          // col cs valid
    bool c5v = (j < WP - 1);     // col cs+5 valid

    // base index (float4 units) of row 0, col cs, this cg
    long rowbase = (long)b * H_ * RS4 + (long)cs * CS4 + cg;
    const float4* base = (const float4*)in;

    float4 acc0 = f4z(), acc1 = f4z(), acc2 = f4z(), acc3 = f4z();

    #pragma unroll
    for (int rr = 0; rr < 18; ++rr) {
        int r = r0 + rr;
        // only rr==0 can be <0 (t==0), only rr==17 can be >=H_ (t==15)
        bool rvalid = (rr == 0) ? (r >= 0) : ((rr == 17) ? (r < H_) : true);
        if (rvalid) {
            const float4* p = base + rowbase + (long)r * RS4;
            float4 rsum = c0v ? p[0] : f4z();
            rsum = f4add(rsum, p[1 * CS4]);
            rsum = f4add(rsum, p[2 * CS4]);
            rsum = f4add(rsum, p[3 * CS4]);
            rsum = f4add(rsum, p[4 * CS4]);
            if (c5v) rsum = f4add(rsum, p[5 * CS4]);
            if (rr <= 5)             acc0 = f4add(acc0, rsum);
            if (rr >= 4 && rr <= 9)  acc1 = f4add(acc1, rsum);
            if (rr >= 8 && rr <= 13) acc2 = f4add(acc2, rsum);
            if (rr >= 12)            acc3 = f4add(acc3, rsum);
        }
    }

    int i0 = t * 4;
    float nc = 6.0f - (j == 0 ? 1.0f : 0.0f) - (j == WP - 1 ? 1.0f : 0.0f);
    float4* pp = (float4*)pooled;
    size_t out0 = ((size_t)(b * HP + i0) * WP + j) * CG + cg;

    #pragma unroll
    for (int k = 0; k < 4; ++k) {
        int i = i0 + k;
        float nr = 6.0f - (i == 0 ? 1.0f : 0.0f) - (i == HP - 1 ? 1.0f : 0.0f);
        float s = 1.0f / (nr * nc);
        float4 a = (k == 0) ? acc0 : (k == 1) ? acc1 : (k == 2) ? acc2 : acc3;
        pp[out0 + (size_t)k * WP * CG] = make_float4(a.x * s, a.y * s, a.z * s, a.w * s);
    }
}

// ---------------- Kernel 2: "unaverage pool" bilinear upsample ----------------
// dest_to_source with s=4, dsi=2, max_src=63: lo=5.5, hi=249.5
__device__ __forceinline__ float d2s(float dest) {
    const float s = 4.0f, dsi = 2.0f, maxs = 63.0f;
    float lo = dsi + s - 0.5f;                       // 5.5
    float hi = dsi + (maxs - 1.0f) * s - 0.5f;       // 249.5
    if (dest < lo) {
        return (dest - dsi) / (s - 0.5f);
    } else if (dest > hi) {
        return (dest - dsi + 0.5f - (maxs - 1.0f) * s) / (s - 0.5f) + maxs - 1.0f;
    } else {
        return (dest - dsi + 0.5f) / s;
    }
}

// Thread = (b, ti, tj, cg): 4x4 output tile (hd=4ti+dy, wd=4tj+dx) from a
// 3x3 pooled neighborhood rows ti-1..ti+1, cols tj-1..tj+1 (zero-padded).
// For every dest row in the tile, floor(d2s) is ti-1 or ti, so the 3 rows /
// 3 cols cover all bilinear taps.
__global__ __launch_bounds__(256) void upsample_kernel(const float* __restrict__ pooled,
                                                       float* __restrict__ out) {
    int gid = blockIdx.x * blockDim.x + threadIdx.x;
    int cg = gid & (CG - 1);
    int tj = (gid >> 4) & (WP - 1);
    int ti = (gid >> 10) & (HP - 1);
    int b  = gid >> 16;

    const float4* pb = (const float4*)pooled + (size_t)b * HP * WP * CG + cg;

    bool rv0 = (ti > 0), rv2 = (ti < HP - 1);
    bool cv0 = (tj > 0), cv2 = (tj < WP - 1);
    float4 z = f4z();

    float4 t00 = (rv0 && cv0) ? pb[((ti - 1) * WP + (tj - 1)) * CG] : z;
    float4 t01 = rv0          ? pb[((ti - 1) * WP + tj) * CG]       : z;
    float4 t02 = (rv0 && cv2) ? pb[((ti - 1) * WP + (tj + 1)) * CG] : z;
    float4 t10 = cv0          ? pb[(ti * WP + (tj - 1)) * CG]       : z;
    float4 t11 =                pb[(ti * WP + tj) * CG];
    float4 t12 = cv2          ? pb[(ti * WP + (tj + 1)) * CG]       : z;
    float4 t20 = (rv2 && cv0) ? pb[((ti + 1) * WP + (tj - 1)) * CG] : z;
    float4 t21 = rv2          ? pb[((ti + 1) * WP + tj) * CG]       : z;
    float4 t22 = (rv2 && cv2) ? pb[((ti + 1) * WP + (tj + 1)) * CG] : z;

    size_t obase = (size_t)b * H_ * W_ * CG + cg;
    float4* ob = (float4*)out;

    #pragma unroll
    for (int dy = 0; dy < 4; ++dy) {
        int hd = 4 * ti + dy;
        float sr = d2s((float)hd);
        float r0f = floorf(sr);
        float fr = sr - r0f;
        bool rhi = (((int)r0f - (ti - 1)) != 0);   // row pair starts at ti (vs ti-1)
        float4 a0 = rhi ? t10 : t00;
        float4 a1 = rhi ? t11 : t01;
        float4 a2 = rhi ? t12 : t02;
        float4 b0 = rhi ? t20 : t10;
        float4 b1 = rhi ? t21 : t11;
        float4 b2 = rhi ? t22 : t12;

        #pragma unroll
        for (int dx = 0; dx < 4; ++dx) {
            int wd = 4 * tj + dx;
            float sc = d2s((float)wd);
            float c0f = floorf(sc);
            float fc = sc - c0f;
            bool chi = (((int)c0f - (tj - 1)) != 0);
            float4 p00 = chi ? a1 : a0;
            float4 p01 = chi ? a2 : a1;
            float4 p10 = chi ? b1 : b0;
            float4 p11 = chi ? b2 : b1;

            float w00 = (1.0f - fr) * (1.0f - fc);
            float w01 = (1.0f - fr) * fc;
            float w10 = fr * (1.0f - fc);
            float w11 = fr * fc;

            float4 v;
            v.x = p00.x * w00 + p01.x * w01 + p10.x * w10 + p11.x * w11;
            v.y = p00.y * w00 + p01.y * w01 + p10.y * w10 + p11.y * w11;
            v.z = p00.z * w00 + p01.z * w01 + p10.z * w10 + p11.z * w11;
            v.w = p00.w * w00 + p01.w * w01 + p10.w * w10 + p11.w * w11;

            ob[obase + ((size_t)(hd * W_ + wd)) * CG] = v;
        }
    }
}

extern "C" void kernel_launch(void* const* d_in, const int* in_sizes, int n_in,
                              void* d_out, int out_size, void* d_ws, size_t ws_size,
                              hipStream_t stream) {
    const float* in  = (const float*)d_in[0];
    float* out       = (float*)d_out;
    float* pooled    = (float*)d_ws;   // 8 MiB used

    // Kernel 1: 8*16*64*16 threads = 131072 -> 512 blocks
    pool_kernel<<<dim3(B_ * (HP / 4) * WP * CG / 256), dim3(256), 0, stream>>>(in, pooled);
    // Kernel 2: 8*64*64*16 threads = 524288 -> 2048 blocks
    upsample_kernel<<<dim3(B_ * HP * WP * CG / 256), dim3(256), 0, stream>>>(pooled, out);
}